// Round 8
// baseline (118.249 us; speedup 1.0000x reference)
//
#include <hip/hip_runtime.h>
#include <hip/hip_bf16.h>

#define NN 256
#define HH 256

typedef __attribute__((ext_vector_type(8))) short short8;
typedef __attribute__((ext_vector_type(4))) float f32x4;

__device__ __forceinline__ ushort f2bf(float x) {
    __hip_bfloat16 h = __float2bfloat16(x);
    return *reinterpret_cast<ushort*>(&h);
}
__device__ __forceinline__ float fast_rcp(float x) {
    return __builtin_amdgcn_rcpf(x);
}
__device__ __forceinline__ float fast_tanh(float x) {
    float e = __expf(2.0f * x);
    return 1.0f - 2.0f * fast_rcp(e + 1.0f);
}
template <int CTRL>
__device__ __forceinline__ float dpp_add(float x) {
    int y = __builtin_amdgcn_update_dpp(0, __float_as_int(x), CTRL, 0xF, 0xF, true);
    return x + __int_as_float(y);
}
template <int CTRL>
__device__ __forceinline__ float dpp_max(float x) {
    int y = __builtin_amdgcn_update_dpp(0, __float_as_int(x), CTRL, 0xF, 0xF, true);
    return fmaxf(x, __int_as_float(y));
}
__device__ __forceinline__ float red16(float v) {
    v = dpp_add<0xB1>(v); v = dpp_add<0x4E>(v);
    v = dpp_add<0x141>(v); v = dpp_add<0x140>(v);
    return v;
}
__device__ __forceinline__ float red16max(float v) {
    v = dpp_max<0xB1>(v); v = dpp_max<0x4E>(v);
    v = dpp_max<0x141>(v); v = dpp_max<0x140>(v);
    return v;
}

// ws (float offsets), total 108,544 floats = 434,176 B
#define WS_P   0        // P[256][64]
#define WS_Q   16384    // Q[256][64]
#define WS_T   32768    // T[256][256]
#define WS_WA  98304    // WA[4][256]
#define WS_WB  99328    // WB[4][256]
#define WS_WGT 100352   // WgT ushort[256][64]

// grid 208: [0,16) WA/WB | [16,80) P/Q | [80,144) WgT | [144,208) T
// (W2 transpose stage deleted: projection now reads raw f32 w in-block)
__global__ __launch_bounds__(256) void precompute_kernel(
    const float* __restrict__ ahs, const float* __restrict__ goal,
    const float* __restrict__ action, const float* __restrict__ Wd,
    const float* __restrict__ b_dist, const float* __restrict__ Wg,
    const float* __restrict__ w, const float* __restrict__ a,
    float* __restrict__ ws)
{
    const int b = blockIdx.x;
    const int t = threadIdx.x;
    const int wid  = t >> 6;
    const int lane = t & 63;
    float* P  = ws + WS_P;
    float* Q  = ws + WS_Q;
    float* T  = ws + WS_T;
    float* WA = ws + WS_WA;
    float* WB = ws + WS_WB;
    ushort* WgT = (ushort*)(ws + WS_WGT);

    if (b < 16) {
        const int z  = b >> 2;
        const int rg = b & 3;
        const int hbase = rg*64 + wid*16;
        const f32x4 aB = *(const f32x4*)(a + lane*4);
        const f32x4 aA = *(const f32x4*)(a + HH + lane*4);
#pragma unroll 4
        for (int rr = 0; rr < 16; ++rr) {
            const int h = hbase + rr;
            const f32x4 w4 = *(const f32x4*)(w + z*HH*HH + h*HH + lane*4);
            float dA = w4.x*aA.x + w4.y*aA.y + w4.z*aA.z + w4.w*aA.w;
            float dB = w4.x*aB.x + w4.y*aB.y + w4.z*aB.z + w4.w*aB.w;
#pragma unroll
            for (int off = 32; off; off >>= 1) {
                dA += __shfl_xor(dA, off);
                dB += __shfl_xor(dB, off);
            }
            if (lane == 0) { WA[z*HH + h] = dA; WB[z*HH + h] = dB; }
        }
    } else if (b < 80) {
        const int i = (b - 16)*4 + wid;
        const int d = lane;
        float a0 = action[2*i], a1 = action[2*i+1];
        float g0 = goal[2*i],   g1 = goal[2*i+1];
        P[i*64 + d] = a0*Wd[0*64+d] + a1*Wd[1*64+d]
                    + g0*Wd[2*64+d] + g1*Wd[3*64+d] + b_dist[d];
        Q[i*64 + d] = a0*Wd[4*64+d] + a1*Wd[5*64+d]
                    + g0*Wd[6*64+d] + g1*Wd[7*64+d];
    } else if (b < 144) {
        const int d = b - 80;
        WgT[t*64 + d] = f2bf(Wg[d*HH + t]);
    } else {
        const int idx = ((b - 144)*256 + t)*4;
        float4 v = *(const float4*)(ahs + idx);
        float4 o;
        o.x = fast_tanh(v.x); o.y = fast_tanh(v.y);
        o.z = fast_tanh(v.z); o.w = fast_tanh(v.w);
        *(float4*)(T + idx) = o;
    }
}

// grid 256 x 512 threads: one block owns the ENTIRE row n.
// Waves 0-3 (hh=0) handle j in [0,128), waves 4-7 (hh=1) handle [128,256) —
// the R1 partial structure duplicated across wave-groups. Softmax merge is
// then block-LOCAL (LDS), and the projection out[n] = sum_zh merged·w runs
// in-block on VALU reading raw f32 w (L2-resident). Deletes the out kernel,
// its launch boundary, the PV/ML round-trip, and precompute's W2 transpose.
__global__ __launch_bounds__(512, 2) void gat_row_kernel(
    const float* __restrict__ ahs, const float* __restrict__ ghs,
    const float* __restrict__ b_gate, const float* __restrict__ bias,
    const float* __restrict__ w, const float* __restrict__ ws,
    float* __restrict__ out)
{
    const int n    = blockIdx.x;
    const int t    = threadIdx.x;
    const int wid4 = t >> 6;        // 0..7
    const int hh   = wid4 >> 2;     // wave-group: j-half
    const int wid  = wid4 & 3;      // wave within group
    const int lane = t & 63;
    const int quad = lane >> 4;
    const int l15  = lane & 15;
    const int zg   = quad;
    const int jj   = l15;
    const int n0   = wid * 64;

    const float* P  = ws + WS_P;
    const float* Q  = ws + WS_Q;
    const float* T  = ws + WS_T;
    const float* WA = ws + WS_WA;
    const float* WB = ws + WS_WB;
    const ushort* WgT = (const ushort*)(ws + WS_WGT);

    __shared__ __align__(16) float part[2][2][4][16][4];
    __shared__ __align__(16) float alpha_w[2][4][16][4];
    __shared__ __align__(16) float vred[16][260];
    __shared__ __align__(16) float ml[2][4][2];
    __shared__ __align__(16) float merged[4][256];
    __shared__ __align__(16) float proj[2][256];
    __shared__ __align__(16) ushort A_l[256*64];   // 256 j-rows, 128B, swizzled

    int hcol[4];
#pragma unroll
    for (int nt = 0; nt < 4; ++nt) hcol[nt] = n0 + nt*16 + l15;

    short8 bfrag[4][2];
    float  wa_reg[4][4];
    float  bgv[4], gval[4];
#pragma unroll
    for (int nt = 0; nt < 4; ++nt) {
#pragma unroll
        for (int kh = 0; kh < 2; ++kh)
            bfrag[nt][kh] = *(const short8*)(WgT + hcol[nt]*64 + kh*32 + quad*8);
#pragma unroll
        for (int z = 0; z < 4; ++z) wa_reg[z][nt] = WA[z*HH + hcol[nt]];
        bgv[nt]  = b_gate[hcol[nt]];
        gval[nt] = ghs[n*HH + hcol[nt]];
    }

    // ---- build A_l: all 256 j-rows x 64 k of bf16(relu(P[n]+Q[j])) ----
    {
        const int jl = t >> 1;          // 0..255 (global j)
        const int kh = t & 1;
        const float* prow = P + n*64 + kh*32;
        const float* qrow = Q + jl*64 + kh*32;
        ushort hv[32];
#pragma unroll
        for (int c = 0; c < 8; ++c) {
            f32x4 pq = *(const f32x4*)(prow + c*4);
            f32x4 qq = *(const f32x4*)(qrow + c*4);
            hv[c*4+0] = f2bf(fmaxf(pq.x + qq.x, 0.f));
            hv[c*4+1] = f2bf(fmaxf(pq.y + qq.y, 0.f));
            hv[c*4+2] = f2bf(fmaxf(pq.z + qq.z, 0.f));
            hv[c*4+3] = f2bf(fmaxf(pq.w + qq.w, 0.f));
        }
        char* rb = (char*)A_l + jl*128;
        const int sw = (jl & 7) << 4;
#pragma unroll
        for (int c2 = 0; c2 < 4; ++c2) {
            const int off = (kh*64 + c2*16) ^ sw;
            *(short8*)(rb + off) = *(const short8*)(hv + c2*8);
        }
    }

    float vacc[4][4];
    {
        float av[4];
#pragma unroll
        for (int nt = 0; nt < 4; ++nt) av[nt] = ahs[n*HH + hcol[nt]];
#pragma unroll
        for (int z = 0; z < 4; ++z)
#pragma unroll
            for (int nt = 0; nt < 4; ++nt)
                vacc[z][nt] = (hh == 0 && quad == 0) ? av[nt] : 0.f;
    }

    // redundant per-wave softmax init: lane (zg,jj) sums h=jj*16..+16
    float cz_r, m_r, l_r;
    {
        float pc = 0.f, ps = 0.f;
        const int hb = jj*16;
#pragma unroll
        for (int i4 = 0; i4 < 4; ++i4) {
            f32x4 av = *(const f32x4*)(ahs + n*HH + hb + i4*4);
            f32x4 wb = *(const f32x4*)(WB + zg*HH + hb + i4*4);
            f32x4 wa = *(const f32x4*)(WA + zg*HH + hb + i4*4);
            pc = fmaf(av.x, wb.x, pc); pc = fmaf(av.y, wb.y, pc);
            pc = fmaf(av.z, wb.z, pc); pc = fmaf(av.w, wb.w, pc);
            ps = fmaf(av.x, wa.x, ps); ps = fmaf(av.y, wa.y, ps);
            ps = fmaf(av.z, wa.z, ps); ps = fmaf(av.w, wa.w, ps);
        }
        pc = red16(pc); ps = red16(ps);
        cz_r = pc;
        if (hh == 0) {
            float sc = pc + ps;
            m_r = sc > 0.f ? sc : 0.2f * sc;
            l_r = 1.0f;
        } else {
            m_r = -__builtin_inff();
            l_r = 0.0f;
        }
    }

    __syncthreads();   // A_l visible to all waves

    // T prefetch for chunk 0
    float tval[4][4];
    {
        const int j0 = hh*128;
#pragma unroll
        for (int r = 0; r < 4; ++r) {
            const int jg = j0 + quad*4 + r;
#pragma unroll
            for (int nt = 0; nt < 4; ++nt)
                tval[nt][r] = T[jg*HH + hcol[nt]];
        }
    }

    for (int cc = 0; cc < 8; ++cc) {
        const int j0  = hh*128 + cc*16;
        const int par = cc & 1;

        // A-frags from swizzled LDS (row = global j)
        const int jl = j0 + l15;
        const char* rb = (const char*)A_l + jl*128;
        const int sw = (l15 & 7) << 4;
        short8 afrag0 = *(const short8*)(rb + ((quad*16) ^ sw));
        short8 afrag1 = *(const short8*)(rb + ((64 + quad*16) ^ sw));

        f32x4 acc[4];
#pragma unroll
        for (int nt = 0; nt < 4; ++nt) {
            f32x4 a4 = (f32x4){0.f,0.f,0.f,0.f};
            a4 = __builtin_amdgcn_mfma_f32_16x16x32_bf16(afrag0, bfrag[nt][0], a4, 0, 0, 0);
            a4 = __builtin_amdgcn_mfma_f32_16x16x32_bf16(afrag1, bfrag[nt][1], a4, 0, 0, 0);
            acc[nt] = a4;
        }

        // gate epilogue (T resident, diag from regs)
        float vals[4][4];
#pragma unroll
        for (int r = 0; r < 4; ++r) {
            const int jg = j0 + quad*4 + r;
            const bool diag = (jg == n);
#pragma unroll
            for (int nt = 0; nt < 4; ++nt) {
                float u = acc[nt][r] + bgv[nt];
                float g = fast_rcp(1.0f + __expf(-u));
                vals[nt][r] = diag ? gval[nt] : g * tval[nt][r];
            }
        }

        // score partials
#pragma unroll
        for (int z = 0; z < 4; ++z) {
            float pp[4];
#pragma unroll
            for (int r = 0; r < 4; ++r) {
                float s = 0.f;
#pragma unroll
                for (int nt = 0; nt < 4; ++nt)
                    s = fmaf(vals[nt][r], wa_reg[z][nt], s);
                pp[r] = red16(s);
            }
            if (l15 == z) {
#pragma unroll
                for (int r = 0; r < 4; ++r)
                    part[hh][par][z][quad*4 + r][wid] = pp[r];
            }
        }
        __syncthreads();   // only barrier per chunk (all 8 waves, symmetric)

        // software-pipelined T prefetch for next chunk
        float tnext[4][4];
        if (cc < 7) {
            const int j1 = j0 + 16;
#pragma unroll
            for (int r = 0; r < 4; ++r) {
                const int jg = j1 + quad*4 + r;
#pragma unroll
                for (int nt = 0; nt < 4; ++nt)
                    tnext[nt][r] = T[jg*HH + hcol[nt]];
            }
        }

        // redundant lane-parallel softmax
        float scl0, scl1, scl2, scl3;
        {
            f32x4 pr = *(const f32x4*)&part[hh][par][zg][jj][0];
            float s = cz_r + ((pr.x + pr.y) + (pr.z + pr.w));
            float e = s > 0.f ? s : 0.2f * s;
            float mx = red16max(e);
            float m_new = fmaxf(m_r, mx);
            float at = __expf(e - m_new);
            float ss = red16(at);
            float scale = __expf(m_r - m_new);
            l_r = l_r * scale + ss;
            m_r = m_new;
            alpha_w[hh][wid][jj][zg] = at;
            scl0 = __shfl(scale, 0);
            scl1 = __shfl(scale, 16);
            scl2 = __shfl(scale, 32);
            scl3 = __shfl(scale, 48);
        }
#pragma unroll
        for (int nt = 0; nt < 4; ++nt) {
            vacc[0][nt] *= scl0; vacc[1][nt] *= scl1;
            vacc[2][nt] *= scl2; vacc[3][nt] *= scl3;
        }
#pragma unroll
        for (int r = 0; r < 4; ++r) {
            f32x4 al = *(const f32x4*)&alpha_w[hh][wid][quad*4 + r][0];
#pragma unroll
            for (int nt = 0; nt < 4; ++nt) {
                float v = vals[nt][r];
                vacc[0][nt] = fmaf(al.x, v, vacc[0][nt]);
                vacc[1][nt] = fmaf(al.y, v, vacc[1][nt]);
                vacc[2][nt] = fmaf(al.z, v, vacc[2][nt]);
                vacc[3][nt] = fmaf(al.w, v, vacc[3][nt]);
            }
        }
        if (cc < 7) {
#pragma unroll
            for (int nt = 0; nt < 4; ++nt)
#pragma unroll
                for (int r = 0; r < 4; ++r)
                    tval[nt][r] = tnext[nt][r];
        }
    }

    // ---- block-local softmax merge across hh halves ----
    if (wid == 0 && l15 == 0) {     // lane quad=zg of wave hh*4 holds (hh, z=zg)
        ml[hh][zg][0] = m_r;
        ml[hh][zg][1] = l_r;
    }
    __syncthreads();

    float shz[4];
#pragma unroll
    for (int z = 0; z < 4; ++z) {
        float m0 = ml[0][z][0], l0 = ml[0][z][1];
        float m1 = ml[1][z][0], l1 = ml[1][z][1];
        float M  = fmaxf(m0, m1);
        float e0 = __expf(m0 - M), e1 = __expf(m1 - M);
        float L  = l0*e0 + l1*e1;
        shz[z] = (hh == 0 ? e0 : e1) * fast_rcp(L);
    }

    // sequential scaled accumulation into vred (avoids 2x vred LDS)
    if (hh == 0) {
#pragma unroll
        for (int z = 0; z < 4; ++z)
#pragma unroll
            for (int nt = 0; nt < 4; ++nt)
                vred[quad*4 + z][hcol[nt]] = shz[z] * vacc[z][nt];
    }
    __syncthreads();
    if (hh == 1) {
#pragma unroll
        for (int z = 0; z < 4; ++z)
#pragma unroll
            for (int nt = 0; nt < 4; ++nt)
                vred[quad*4 + z][hcol[nt]] += shz[z] * vacc[z][nt];
    }
    __syncthreads();

    if (t < 256) {
#pragma unroll
        for (int z = 0; z < 4; ++z)
            merged[z][t] = (vred[0*4+z][t] + vred[1*4+z][t])
                         + (vred[2*4+z][t] + vred[3*4+z][t]);
    }
    __syncthreads();

    // ---- in-block projection: out[n][f] = relu(0.25 * sum_z sum_h merged·w) + bias
    // thread (zh, f): zh covers z in {2zh, 2zh+1}; w reads coalesced along f.
    {
        const int fP = t & 255;
        const int zh = t >> 8;
        const float* w0 = w + (size_t)(zh*2 + 0)*HH*HH + fP;
        const float* w1 = w + (size_t)(zh*2 + 1)*HH*HH + fP;
        const float* m0p = &merged[zh*2 + 0][0];
        const float* m1p = &merged[zh*2 + 1][0];
        float ac0 = 0.f, ac1 = 0.f;
#pragma unroll 8
        for (int h = 0; h < 256; ++h) {
            ac0 = fmaf(m0p[h], w0[(size_t)h*HH], ac0);
            ac1 = fmaf(m1p[h], w1[(size_t)h*HH], ac1);
        }
        proj[zh][fP] = ac0 + ac1;
    }
    __syncthreads();
    if (t < 256) {
        out[(size_t)n*HH + t] = fmaxf(0.25f * (proj[0][t] + proj[1][t]), 0.f) + bias[t];
    }
}

extern "C" void kernel_launch(void* const* d_in, const int* in_sizes, int n_in,
                              void* d_out, int out_size, void* d_ws, size_t ws_size,
                              hipStream_t stream)
{
    const float* ahs    = (const float*)d_in[0];
    const float* ghs    = (const float*)d_in[1];
    const float* goal   = (const float*)d_in[2];
    const float* action = (const float*)d_in[3];
    const float* Wd     = (const float*)d_in[4];
    const float* b_dist = (const float*)d_in[5];
    const float* Wg     = (const float*)d_in[6];
    const float* b_gate = (const float*)d_in[7];
    const float* w      = (const float*)d_in[8];
    const float* a      = (const float*)d_in[9];
    const float* bias   = (const float*)d_in[10];
    float* ws   = (float*)d_ws;     // needs 434,176 bytes
    float* outp = (float*)d_out;

    precompute_kernel<<<208, 256, 0, stream>>>(ahs, goal, action, Wd, b_dist, Wg, w, a, ws);
    gat_row_kernel<<<256, 512, 0, stream>>>(ahs, ghs, b_gate, bias, w, ws, outp);
}

// Round 9
// 114.454 us; speedup vs baseline: 1.0332x; 1.0332x over previous
//
#include <hip/hip_runtime.h>
#include <hip/hip_bf16.h>

#define NN 256
#define HH 256

typedef __attribute__((ext_vector_type(8))) short short8;
typedef __attribute__((ext_vector_type(4))) float f32x4;

__device__ __forceinline__ ushort f2bf(float x) {
    __hip_bfloat16 h = __float2bfloat16(x);
    return *reinterpret_cast<ushort*>(&h);
}
__device__ __forceinline__ float bf2f(ushort u) {
    __hip_bfloat16 h = *reinterpret_cast<__hip_bfloat16*>(&u);
    return __bfloat162float(h);
}
__device__ __forceinline__ float fast_rcp(float x) {
    return __builtin_amdgcn_rcpf(x);
}
__device__ __forceinline__ float fast_tanh(float x) {
    float e = __expf(2.0f * x);
    return 1.0f - 2.0f * fast_rcp(e + 1.0f);
}
template <int CTRL>
__device__ __forceinline__ float dpp_add(float x) {
    int y = __builtin_amdgcn_update_dpp(0, __float_as_int(x), CTRL, 0xF, 0xF, true);
    return x + __int_as_float(y);
}
template <int CTRL>
__device__ __forceinline__ float dpp_max(float x) {
    int y = __builtin_amdgcn_update_dpp(0, __float_as_int(x), CTRL, 0xF, 0xF, true);
    return fmaxf(x, __int_as_float(y));
}
__device__ __forceinline__ float red16(float v) {
    v = dpp_add<0xB1>(v); v = dpp_add<0x4E>(v);
    v = dpp_add<0x141>(v); v = dpp_add<0x140>(v);
    return v;
}
__device__ __forceinline__ float red16max(float v) {
    v = dpp_max<0xB1>(v); v = dpp_max<0x4E>(v);
    v = dpp_max<0x141>(v); v = dpp_max<0x140>(v);
    return v;
}

// ws (float offsets), total 899,072 floats = 3,596,288 B
#define WS_P   0        // P[256][64]
#define WS_Q   16384    // Q[256][64]
#define WS_T   32768    // T[256][256]
#define WS_WA  98304    // WA[4][256]
#define WS_WB  99328    // WB[4][256]
#define WS_WGT 100352   // WgT ushort[256][64]
#define WS_PV  108544   // PV[2][4][256][256]
#define WS_ML  632832   // ML[2][4][256][2]
#define WS_W2H 636928   // W2hi ushort[256f][1024k]
#define WS_W2L 768000   // W2lo ushort[256f][1024k]

// grid 272: [0,16) WA/WB | [16,80) W2 transpose | [80,144) P/Q | [144,208) WgT | [208,272) T
__global__ __launch_bounds__(256) void precompute_kernel(
    const float* __restrict__ ahs, const float* __restrict__ goal,
    const float* __restrict__ action, const float* __restrict__ Wd,
    const float* __restrict__ b_dist, const float* __restrict__ Wg,
    const float* __restrict__ w, const float* __restrict__ a,
    float* __restrict__ ws)
{
    const int b = blockIdx.x;
    const int t = threadIdx.x;
    const int wid  = t >> 6;
    const int lane = t & 63;
    float* P  = ws + WS_P;
    float* Q  = ws + WS_Q;
    float* T  = ws + WS_T;
    float* WA = ws + WS_WA;
    float* WB = ws + WS_WB;
    ushort* WgT  = (ushort*)(ws + WS_WGT);
    ushort* W2hi = (ushort*)(ws + WS_W2H);
    ushort* W2lo = (ushort*)(ws + WS_W2L);

    __shared__ __align__(16) float tile[64][65];

    if (b < 16) {
        const int z  = b >> 2;
        const int rg = b & 3;
        const int hbase = rg*64 + wid*16;
        const f32x4 aB = *(const f32x4*)(a + lane*4);
        const f32x4 aA = *(const f32x4*)(a + HH + lane*4);
#pragma unroll 4
        for (int rr = 0; rr < 16; ++rr) {
            const int h = hbase + rr;
            const f32x4 w4 = *(const f32x4*)(w + z*HH*HH + h*HH + lane*4);
            float dA = w4.x*aA.x + w4.y*aA.y + w4.z*aA.z + w4.w*aA.w;
            float dB = w4.x*aB.x + w4.y*aB.y + w4.z*aB.z + w4.w*aB.w;
#pragma unroll
            for (int off = 32; off; off >>= 1) {
                dA += __shfl_xor(dA, off);
                dB += __shfl_xor(dB, off);
            }
            if (lane == 0) { WA[z*HH + h] = dA; WB[z*HH + h] = dB; }
        }
    } else if (b < 80) {
        const int idx = b - 16;
        const int k0  = (idx >> 2) * 64;
        const int f0  = (idx & 3) * 64;
        const int ff  = t & 63;
#pragma unroll 4
        for (int i = 0; i < 16; ++i) {
            const int kk = i*4 + wid;
            tile[kk][ff] = w[(k0 + kk)*HH + f0 + ff];
        }
        __syncthreads();
#pragma unroll 4
        for (int i = 0; i < 16; ++i) {
            const int fl = i*4 + wid;
            float x = tile[ff][fl];
            ushort hi = f2bf(x);
            ushort lo = f2bf(x - bf2f(hi));
            W2hi[(size_t)(f0 + fl)*1024 + k0 + ff] = hi;
            W2lo[(size_t)(f0 + fl)*1024 + k0 + ff] = lo;
        }
    } else if (b < 144) {
        const int i = (b - 80)*4 + wid;
        const int d = lane;
        float a0 = action[2*i], a1 = action[2*i+1];
        float g0 = goal[2*i],   g1 = goal[2*i+1];
        P[i*64 + d] = a0*Wd[0*64+d] + a1*Wd[1*64+d]
                    + g0*Wd[2*64+d] + g1*Wd[3*64+d] + b_dist[d];
        Q[i*64 + d] = a0*Wd[4*64+d] + a1*Wd[5*64+d]
                    + g0*Wd[6*64+d] + g1*Wd[7*64+d];
    } else if (b < 208) {
        const int d = b - 144;
        WgT[t*64 + d] = f2bf(Wg[d*HH + t]);
    } else {
        const int idx = ((b - 208)*256 + t)*4;
        float4 v = *(const float4*)(ahs + idx);
        float4 o;
        o.x = fast_tanh(v.x); o.y = fast_tanh(v.y);
        o.z = fast_tanh(v.z); o.w = fast_tanh(v.w);
        *(float4*)(T + idx) = o;
    }
}

// grid 512: block = (n, half hh); j in [hh*128, +128), 8 one-barrier chunks of 16.
// A = bf16(relu(P[n]+Q[j])) staged once per block in swizzled LDS. T loads
// software-pipelined one chunk ahead. Sigmoid via v_rcp_f32.
__global__ __launch_bounds__(256, 2) void gat_partial_kernel(
    const float* __restrict__ ahs, const float* __restrict__ ghs,
    const float* __restrict__ b_gate, float* __restrict__ ws)
{
    const int n    = blockIdx.x >> 1;
    const int hh   = blockIdx.x & 1;
    const int t    = threadIdx.x;
    const int wid  = t >> 6;
    const int lane = t & 63;
    const int quad = lane >> 4;
    const int l15  = lane & 15;
    const int zg   = quad;
    const int jj   = l15;
    const int n0   = wid * 64;

    const float* P  = ws + WS_P;
    const float* Q  = ws + WS_Q;
    const float* T  = ws + WS_T;
    const float* WA = ws + WS_WA;
    const float* WB = ws + WS_WB;
    const ushort* WgT = (const ushort*)(ws + WS_WGT);
    float* PV = ws + WS_PV;
    float* ML = ws + WS_ML;

    __shared__ __align__(16) float part[2][4][16][4];
    __shared__ __align__(16) float alpha_w[4][16][4];
    __shared__ __align__(16) float vred[16][260];
    __shared__ __align__(16) ushort A_l[128*64];   // bf16, 128B rows, XOR-swizzled

    int hcol[4];
#pragma unroll
    for (int nt = 0; nt < 4; ++nt) hcol[nt] = n0 + nt*16 + l15;

    short8 bfrag[4][2];
    float  wa_reg[4][4];
    float  bgv[4], gval[4];
#pragma unroll
    for (int nt = 0; nt < 4; ++nt) {
#pragma unroll
        for (int kh = 0; kh < 2; ++kh)
            bfrag[nt][kh] = *(const short8*)(WgT + hcol[nt]*64 + kh*32 + quad*8);
#pragma unroll
        for (int z = 0; z < 4; ++z) wa_reg[z][nt] = WA[z*HH + hcol[nt]];
        bgv[nt]  = b_gate[hcol[nt]];
        gval[nt] = ghs[n*HH + hcol[nt]];
    }

    // ---- build A_l: 128 rows (j local) x 64 k of bf16(relu(P[n]+Q[j])) ----
    {
        const int jl = t >> 1;          // 0..127
        const int kh = t & 1;           // which 32-k half
        const float* prow = P + n*64 + kh*32;
        const float* qrow = Q + (hh*128 + jl)*64 + kh*32;
        ushort hv[32];
#pragma unroll
        for (int c = 0; c < 8; ++c) {
            f32x4 pq = *(const f32x4*)(prow + c*4);
            f32x4 qq = *(const f32x4*)(qrow + c*4);
            hv[c*4+0] = f2bf(fmaxf(pq.x + qq.x, 0.f));
            hv[c*4+1] = f2bf(fmaxf(pq.y + qq.y, 0.f));
            hv[c*4+2] = f2bf(fmaxf(pq.z + qq.z, 0.f));
            hv[c*4+3] = f2bf(fmaxf(pq.w + qq.w, 0.f));
        }
        char* rb = (char*)A_l + jl*128;
        const int sw = (jl & 7) << 4;
#pragma unroll
        for (int c2 = 0; c2 < 4; ++c2) {
            const int off = (kh*64 + c2*16) ^ sw;
            *(short8*)(rb + off) = *(const short8*)(hv + c2*8);
        }
    }

    float vacc[4][4];
    {
        float av[4];
#pragma unroll
        for (int nt = 0; nt < 4; ++nt) av[nt] = ahs[n*HH + hcol[nt]];
#pragma unroll
        for (int z = 0; z < 4; ++z)
#pragma unroll
            for (int nt = 0; nt < 4; ++nt)
                vacc[z][nt] = (hh == 0 && quad == 0) ? av[nt] : 0.f;
    }

    // redundant per-wave softmax init: lane (zg,jj) sums h=jj*16..+16
    float cz_r, m_r, l_r;
    {
        float pc = 0.f, ps = 0.f;
        const int hb = jj*16;
#pragma unroll
        for (int i4 = 0; i4 < 4; ++i4) {
            f32x4 av = *(const f32x4*)(ahs + n*HH + hb + i4*4);
            f32x4 wb = *(const f32x4*)(WB + zg*HH + hb + i4*4);
            f32x4 wa = *(const f32x4*)(WA + zg*HH + hb + i4*4);
            pc = fmaf(av.x, wb.x, pc); pc = fmaf(av.y, wb.y, pc);
            pc = fmaf(av.z, wb.z, pc); pc = fmaf(av.w, wb.w, pc);
            ps = fmaf(av.x, wa.x, ps); ps = fmaf(av.y, wa.y, ps);
            ps = fmaf(av.z, wa.z, ps); ps = fmaf(av.w, wa.w, ps);
        }
        pc = red16(pc); ps = red16(ps);
        cz_r = pc;
        if (hh == 0) {
            float sc = pc + ps;
            m_r = sc > 0.f ? sc : 0.2f * sc;
            l_r = 1.0f;
        } else {
            m_r = -__builtin_inff();
            l_r = 0.0f;
        }
    }

    __syncthreads();   // A_l visible to all waves

    // T prefetch for chunk 0
    float tval[4][4];
    {
        const int j0 = hh*128;
#pragma unroll
        for (int r = 0; r < 4; ++r) {
            const int jg = j0 + quad*4 + r;
#pragma unroll
            for (int nt = 0; nt < 4; ++nt)
                tval[nt][r] = T[jg*HH + hcol[nt]];
        }
    }

    for (int cc = 0; cc < 8; ++cc) {
        const int j0  = hh*128 + cc*16;
        const int par = cc & 1;

        // A-frags from swizzled LDS
        const int jl = cc*16 + l15;
        const char* rb = (const char*)A_l + jl*128;
        const int sw = (l15 & 7) << 4;
        short8 afrag0 = *(const short8*)(rb + ((quad*16) ^ sw));
        short8 afrag1 = *(const short8*)(rb + ((64 + quad*16) ^ sw));

        f32x4 acc[4];
#pragma unroll
        for (int nt = 0; nt < 4; ++nt) {
            f32x4 a4 = (f32x4){0.f,0.f,0.f,0.f};
            a4 = __builtin_amdgcn_mfma_f32_16x16x32_bf16(afrag0, bfrag[nt][0], a4, 0, 0, 0);
            a4 = __builtin_amdgcn_mfma_f32_16x16x32_bf16(afrag1, bfrag[nt][1], a4, 0, 0, 0);
            acc[nt] = a4;
        }

        // gate epilogue (T resident, diag from regs)
        float vals[4][4];
#pragma unroll
        for (int r = 0; r < 4; ++r) {
            const int jg = j0 + quad*4 + r;
            const bool diag = (jg == n);
#pragma unroll
            for (int nt = 0; nt < 4; ++nt) {
                float u = acc[nt][r] + bgv[nt];
                float g = fast_rcp(1.0f + __expf(-u));
                vals[nt][r] = diag ? gval[nt] : g * tval[nt][r];
            }
        }

        // score partials
#pragma unroll
        for (int z = 0; z < 4; ++z) {
            float pp[4];
#pragma unroll
            for (int r = 0; r < 4; ++r) {
                float s = 0.f;
#pragma unroll
                for (int nt = 0; nt < 4; ++nt)
                    s = fmaf(vals[nt][r], wa_reg[z][nt], s);
                pp[r] = red16(s);
            }
            if (l15 == z) {
#pragma unroll
                for (int r = 0; r < 4; ++r)
                    part[par][z][quad*4 + r][wid] = pp[r];
            }
        }
        __syncthreads();   // only barrier per chunk

        // software-pipelined T prefetch for next chunk (covered by softmax/vacc)
        float tnext[4][4];
        if (cc < 7) {
            const int j1 = j0 + 16;
#pragma unroll
            for (int r = 0; r < 4; ++r) {
                const int jg = j1 + quad*4 + r;
#pragma unroll
                for (int nt = 0; nt < 4; ++nt)
                    tnext[nt][r] = T[jg*HH + hcol[nt]];
            }
        }

        // redundant lane-parallel softmax
        float scl0, scl1, scl2, scl3;
        {
            f32x4 pr = *(const f32x4*)&part[par][zg][jj][0];
            float s = cz_r + ((pr.x + pr.y) + (pr.z + pr.w));
            float e = s > 0.f ? s : 0.2f * s;
            float mx = red16max(e);
            float m_new = fmaxf(m_r, mx);
            float at = __expf(e - m_new);
            float ss = red16(at);
            float scale = __expf(m_r - m_new);
            l_r = l_r * scale + ss;
            m_r = m_new;
            alpha_w[wid][jj][zg] = at;
            scl0 = __shfl(scale, 0);
            scl1 = __shfl(scale, 16);
            scl2 = __shfl(scale, 32);
            scl3 = __shfl(scale, 48);
        }
#pragma unroll
        for (int nt = 0; nt < 4; ++nt) {
            vacc[0][nt] *= scl0; vacc[1][nt] *= scl1;
            vacc[2][nt] *= scl2; vacc[3][nt] *= scl3;
        }
#pragma unroll
        for (int r = 0; r < 4; ++r) {
            f32x4 al = *(const f32x4*)&alpha_w[wid][quad*4 + r][0];
#pragma unroll
            for (int nt = 0; nt < 4; ++nt) {
                float v = vals[nt][r];
                vacc[0][nt] = fmaf(al.x, v, vacc[0][nt]);
                vacc[1][nt] = fmaf(al.y, v, vacc[1][nt]);
                vacc[2][nt] = fmaf(al.z, v, vacc[2][nt]);
                vacc[3][nt] = fmaf(al.w, v, vacc[3][nt]);
            }
        }
        if (cc < 7) {
#pragma unroll
            for (int nt = 0; nt < 4; ++nt)
#pragma unroll
                for (int r = 0; r < 4; ++r)
                    tval[nt][r] = tnext[nt][r];
        }
    }

    // cross-quad reduce, write PV + ML
#pragma unroll
    for (int z = 0; z < 4; ++z)
#pragma unroll
        for (int nt = 0; nt < 4; ++nt)
            vred[quad*4 + z][hcol[nt]] = vacc[z][nt];
    __syncthreads();
#pragma unroll
    for (int z = 0; z < 4; ++z) {
        float s = (vred[0*4+z][t] + vred[1*4+z][t]) + (vred[2*4+z][t] + vred[3*4+z][t]);
        PV[((size_t)(hh*4 + z)*NN + n)*HH + t] = s;
    }
    if (wid == 0 && l15 == 0) {
        ML[((hh*4 + zg)*NN + n)*2 + 0] = m_r;
        ML[((hh*4 + zg)*NN + n)*2 + 1] = l_r;
    }
}

// grid 256: (16 n-tiles) x (16 f-tiles). Fused merge + split-bf16 MFMA projection.
__global__ __launch_bounds__(256) void gat_out_kernel(
    const float* __restrict__ bias, const float* __restrict__ ws,
    float* __restrict__ out)
{
    const int n0 = (blockIdx.x >> 4) * 16;
    const int f0 = (blockIdx.x & 15) * 16;
    const int t    = threadIdx.x;
    const int wid  = t >> 6;
    const int lane = t & 63;
    const int quad = lane >> 4;
    const int l15  = lane & 15;

    const float* PV = ws + WS_PV;
    const float* ML = ws + WS_ML;
    const ushort* W2hi = (const ushort*)(ws + WS_W2H);
    const ushort* W2lo = (const ushort*)(ws + WS_W2L);

    __shared__ __align__(16) float redc[3][16][17];
    __shared__ __align__(16) float sq[16][4][2];

    // merge scales: t = n_i*8 + z*2 + q (t < 128); q-pairs adjacent lanes
    if (t < 128) {
        const int n_i = t >> 3, z = (t >> 1) & 3, q = t & 1;
        float m = ML[((q*4 + z)*NN + n0 + n_i)*2 + 0];
        float l = ML[((q*4 + z)*NN + n0 + n_i)*2 + 1];
        float mm = fmaxf(m, __shfl_xor(m, 1));
        float s  = __expf(m - mm);
        float ls = l * s;
        ls += __shfl_xor(ls, 1);
        sq[n_i][z][q] = s * fast_rcp(ls);
    }
    __syncthreads();

    f32x4 acc = (f32x4){0.f,0.f,0.f,0.f};

    const float s0 = sq[l15][wid][0];
    const float s1 = sq[l15][wid][1];
    const float* pv0 = PV + ((size_t)(0*4 + wid)*NN + n0 + l15)*HH;
    const float* pv1 = PV + ((size_t)(1*4 + wid)*NN + n0 + l15)*HH;

    for (int ks = 0; ks < 8; ++ks) {
        const int kp = ks*32 + quad*8;
        f32x4 p0a = *(const f32x4*)(pv0 + kp);
        f32x4 p0b = *(const f32x4*)(pv0 + kp + 4);
        f32x4 p1a = *(const f32x4*)(pv1 + kp);
        f32x4 p1b = *(const f32x4*)(pv1 + kp + 4);
        float v[8];
        v[0] = s0*p0a.x + s1*p1a.x; v[1] = s0*p0a.y + s1*p1a.y;
        v[2] = s0*p0a.z + s1*p1a.z; v[3] = s0*p0a.w + s1*p1a.w;
        v[4] = s0*p0b.x + s1*p1b.x; v[5] = s0*p0b.y + s1*p1b.y;
        v[6] = s0*p0b.z + s1*p1b.z; v[7] = s0*p0b.w + s1*p1b.w;
        ushort hi[8], lo[8];
#pragma unroll
        for (int c = 0; c < 8; ++c) {
            hi[c] = f2bf(v[c]);
            lo[c] = f2bf(v[c] - bf2f(hi[c]));
        }
        short8 ah = *(short8*)hi;
        short8 al = *(short8*)lo;
        const size_t boff = (size_t)(f0 + l15)*1024 + wid*256 + kp;
        short8 bh = *(const short8*)(W2hi + boff);
        short8 bl = *(const short8*)(W2lo + boff);
        acc = __builtin_amdgcn_mfma_f32_16x16x32_bf16(ah, bh, acc, 0, 0, 0);
        acc = __builtin_amdgcn_mfma_f32_16x16x32_bf16(ah, bl, acc, 0, 0, 0);
        acc = __builtin_amdgcn_mfma_f32_16x16x32_bf16(al, bh, acc, 0, 0, 0);
    }

    if (wid > 0) {
#pragma unroll
        for (int r = 0; r < 4; ++r)
            redc[wid-1][quad*4 + r][l15] = acc[r];
    }
    __syncthreads();
    if (wid == 0) {
        const int f = f0 + l15;
        float bv = bias[f];
#pragma unroll
        for (int r = 0; r < 4; ++r) {
            const int row = quad*4 + r;
            float s = acc[r]
                    + redc[0][row][l15]
                    + redc[1][row][l15]
                    + redc[2][row][l15];
            out[(size_t)(n0 + row)*HH + f] = fmaxf(0.25f * s, 0.f) + bv;
        }
    }
}

extern "C" void kernel_launch(void* const* d_in, const int* in_sizes, int n_in,
                              void* d_out, int out_size, void* d_ws, size_t ws_size,
                              hipStream_t stream)
{
    const float* ahs    = (const float*)d_in[0];
    const float* ghs    = (const float*)d_in[1];
    const float* goal   = (const float*)d_in[2];
    const float* action = (const float*)d_in[3];
    const float* Wd     = (const float*)d_in[4];
    const float* b_dist = (const float*)d_in[5];
    const float* Wg     = (const float*)d_in[6];
    const float* b_gate = (const float*)d_in[7];
    const float* w      = (const float*)d_in[8];
    const float* a      = (const float*)d_in[9];
    const float* bias   = (const float*)d_in[10];
    float* ws   = (float*)d_ws;     // needs 3,596,288 bytes
    float* outp = (float*)d_out;

    precompute_kernel<<<272, 256, 0, stream>>>(ahs, goal, action, Wd, b_dist, Wg, w, a, ws);
    gat_partial_kernel<<<512, 256, 0, stream>>>(ahs, ghs, b_gate, ws);
    gat_out_kernel<<<256, 256, 0, stream>>>(bias, ws, outp);
}